// Round 1
// baseline (18085.265 us; speedup 1.0000x reference)
//
#include <hip/hip_runtime.h>

// Problem constants (fixed by the reference file)
#define NPTS 524288
#define NUMC 128
#define FD   8
#define NBLK 2048          // NPTS / 256
#define ITERS 5

static_assert(NPTS == NBLK * 256, "grid must tile N exactly");

// ---- workspace layout (bytes) ----
// 0       : centers   float[1024]
// 4096    : flag      int
// 8192    : cnt_inr   int[128]
// 8704    : ctot      int[128]
// 9216    : cbase     int[128]
// 9728    : sums      float[1024]
// 16384   : blockhist int[128*2048]   (1 MB) — cluster-major
// 1064960 : idxlist   int[NPTS]       (2 MB)
// total ~3.2 MB

// init: copy centers, clear converged flag
__global__ void k_init(const float* __restrict__ cin, float* __restrict__ cen, int* __restrict__ flag) {
    int t = blockIdx.x * 256 + threadIdx.x;
    if (t < NUMC * FD) cen[t] = cin[t];
    if (t == 0) *flag = 0;
}

__global__ void k_zero(int* __restrict__ cnt_inr) {
    int t = threadIdx.x;
    if (t < NUMC) cnt_inr[t] = 0;
}

// Pass A: per-center count of points with sqrt(dx^2+dy^2) <= 0.32 (exact recipe, matches assignment)
__global__ void k_count(const float* __restrict__ data, const float* __restrict__ cen,
                        int* __restrict__ cnt_inr, const int* __restrict__ flag) {
    if (*flag) return;
    __shared__ float cx[NUMC], cy[NUMC];
    __shared__ int hist[NUMC];
    int tid = threadIdx.x;
    if (tid < NUMC) { cx[tid] = cen[tid * FD]; cy[tid] = cen[tid * FD + 1]; hist[tid] = 0; }
    __syncthreads();
    size_t j = (size_t)blockIdx.x * 256 + tid;
    float2 p = *(const float2*)(data + j * FD);
    int lane = tid & 63;
    for (int i = 0; i < NUMC; i++) {
        float dx = __fsub_rn(p.x, cx[i]);
        float dy = __fsub_rn(p.y, cy[i]);
        float s  = __fadd_rn(__fmul_rn(dx, dx), __fmul_rn(dy, dy));
        bool in  = (__fsqrt_rn(s) <= 0.32f);
        unsigned long long m = __ballot(in);
        if (lane == 0 && m) atomicAdd(&hist[i], __popcll(m));
    }
    __syncthreads();
    if (tid < NUMC && hist[tid]) atomicAdd(&cnt_inr[tid], hist[tid]);
}

// Pass B: sequential-per-center assignment chain with the freeze quirk.
// Also emits a per-block, cluster-major label histogram for the stable counting sort.
__global__ void k_assign(const float* __restrict__ data, const float* __restrict__ cen,
                         const int* __restrict__ cnt_inr, int* __restrict__ labels,
                         int* __restrict__ blockhist, const int* __restrict__ flag) {
    if (*flag) return;
    __shared__ float C[NUMC * FD];
    __shared__ int enough[NUMC];
    __shared__ int hist[NUMC];
    int tid = threadIdx.x;
    for (int e = tid; e < NUMC * FD; e += 256) C[e] = cen[e];
    if (tid < NUMC) { enough[tid] = (cnt_inr[tid] > 1); hist[tid] = 0; }
    __syncthreads();
    size_t j = (size_t)blockIdx.x * 256 + tid;
    float4 a = *(const float4*)(data + j * FD);
    float4 b = *(const float4*)(data + j * FD + 4);
    float x[8] = {a.x, a.y, a.z, a.w, b.x, b.y, b.z, b.w};
    int lab = -1;
    float dval = 1000.0f;
    for (int i = 0; i < NUMC; i++) {
        const float* c = &C[i * FD];
        float dx = __fsub_rn(x[0], c[0]);
        float dy = __fsub_rn(x[1], c[1]);
        float s  = __fadd_rn(__fmul_rn(dx, dx), __fmul_rn(dy, dy));
        float sp = __fsqrt_rn(s);
        if (sp <= 0.32f && enough[i]) {
            // D = sqrt(sum_f ((x_f - c_f) + 1e-6)^2), strictly sequential fp32, no FMA
            float t0 = __fadd_rn(__fsub_rn(x[0], c[0]), 1e-6f);
            float ss = __fmul_rn(t0, t0);
            #pragma unroll
            for (int f = 1; f < 8; f++) {
                float tf = __fadd_rn(__fsub_rn(x[f], c[f]), 1e-6f);
                ss = __fadd_rn(ss, __fmul_rn(tf, tf));
            }
            float D = __fsqrt_rn(ss);
            if (D < dval) { dval = D; lab = i; }
            else break;   // reference sets dval=0 -> no later center can ever update
        }
    }
    labels[j] = lab;
    if (lab >= 0) atomicAdd(&hist[lab], 1);
    __syncthreads();
    if (tid < NUMC) blockhist[tid * NBLK + blockIdx.x] = hist[tid];
}

// Per-cluster exclusive scan over the 2048 block counts (ints -> exact, order-free)
__global__ void k_scan(int* __restrict__ blockhist, int* __restrict__ ctot, const int* __restrict__ flag) {
    if (*flag) return;
    int c = blockIdx.x, tid = threadIdx.x;
    __shared__ int ts[256];
    int base = c * NBLK + tid * 8;
    int v[8], s = 0;
    #pragma unroll
    for (int u = 0; u < 8; u++) { v[u] = blockhist[base + u]; s += v[u]; }
    ts[tid] = s;
    __syncthreads();
    for (int off = 1; off < 256; off <<= 1) {
        int t = (tid >= off) ? ts[tid - off] : 0;
        __syncthreads();
        ts[tid] += t;
        __syncthreads();
    }
    int run = (tid == 0) ? 0 : ts[tid - 1];
    #pragma unroll
    for (int u = 0; u < 8; u++) { int t = v[u]; blockhist[base + u] = run; run += t; }
    if (tid == 255) ctot[c] = run;
}

__global__ void k_base(const int* __restrict__ ctot, int* __restrict__ cbase, const int* __restrict__ flag) {
    if (*flag) return;
    if (threadIdx.x == 0) {
        int r = 0;
        for (int c = 0; c < NUMC; c++) { cbase[c] = r; r += ctot[c]; }
    }
}

// Stable scatter: member indices per cluster, ascending global point index
__global__ void k_scatter(const int* __restrict__ labels, const int* __restrict__ blockhist,
                          const int* __restrict__ cbase, int* __restrict__ idxlist,
                          const int* __restrict__ flag) {
    if (*flag) return;
    __shared__ int sl[256];
    int tid = threadIdx.x;
    int j = blockIdx.x * 256 + tid;
    sl[tid] = labels[j];
    __syncthreads();
    int c = sl[tid];
    if (c >= 0) {
        int rank = 0;
        for (int t = 0; t < tid; t++) rank += (sl[t] == c);
        idxlist[cbase[c] + blockhist[c * NBLK + blockIdx.x] + rank] = j;
    }
}

// Exact sequential fp32 segment sums: one wave per cluster; loads are parallel,
// the adds are serialized in member order via shfl (bit-exact vs sequential scatter-add).
__global__ void k_sums(const float* __restrict__ data, const int* __restrict__ idxlist,
                       const int* __restrict__ cbase, const int* __restrict__ ctot,
                       float* __restrict__ sums, const int* __restrict__ flag) {
    if (*flag) return;
    int c = blockIdx.x;
    int lane = threadIdx.x;        // 64 threads = 1 wave
    int m = ctot[c], base = cbase[c];
    int f = lane & 7;
    float acc = 0.0f;
    for (int k0 = 0; k0 < m; k0 += 64) {
        int kk = k0 + lane;
        int idx = (kk < m) ? idxlist[base + kk] : 0;
        #pragma unroll
        for (int s = 0; s < 8; s++) {
            int kr  = k0 + s * 8 + (lane >> 3);
            int rid = __shfl(idx, s * 8 + (lane >> 3), 64);
            float val = (kr < m) ? data[(size_t)rid * FD + f] : 0.0f;  // +0.0f adds are exact no-ops
            #pragma unroll
            for (int r = 0; r < 8; r++)
                acc = __fadd_rn(acc, __shfl(val, r * 8 + lane, 64));   // lanes 0..7 hold the real chains
        }
    }
    if (lane < 8) sums[c * FD + lane] = acc;
}

// Center update + convergence flag (1 block). Skipped entirely once converged,
// which implements the reference's freeze-on-carry semantics.
__global__ void k_update(float* __restrict__ cen, const float* __restrict__ sums,
                         const int* __restrict__ ctot, int* __restrict__ flag) {
    if (*flag) return;
    __shared__ float red[256];
    int tid = threadIdx.x;
    float sq = 0.0f;
    float newv[4];
    int   eidx[4];
    int ne = 0;
    for (int e = tid; e < NUMC * FD; e += 256) {
        int c = e >> 3;
        float oldv = cen[e];
        float cntf = (float)ctot[c];
        float mean = __fdiv_rn(sums[e], fmaxf(cntf, 1.0f));
        float nc = (cntf > 0.0f) ? mean : oldv;
        float d = __fsub_rn(nc, oldv);
        sq = __fadd_rn(sq, __fmul_rn(d, d));   // only compared vs 1e-4, order-insensitive in practice
        newv[ne] = nc; eidx[ne] = e; ne++;
    }
    red[tid] = sq;
    __syncthreads();
    for (int off = 128; off > 0; off >>= 1) {
        if (tid < off) red[tid] += red[tid + off];
        __syncthreads();
    }
    for (int u = 0; u < ne; u++) cen[eidx[u]] = newv[u];
    if (tid == 0) {
        float diff = __fsqrt_rn(red[0]);
        if (diff < 1e-4f) *flag = 1;
    }
}

// Finalize: labels were staged as int32 in d_out[0..N); convert in place to float,
// then append final centers.
__global__ void k_finish(float* __restrict__ out, const float* __restrict__ cen) {
    size_t i = (size_t)blockIdx.x * 256 + threadIdx.x;
    if (i < NPTS) {
        int v = ((const int*)out)[i];
        out[i] = (float)v;
    } else if (i < NPTS + NUMC * FD) {
        out[i] = cen[i - NPTS];
    }
}

extern "C" void kernel_launch(void* const* d_in, const int* in_sizes, int n_in,
                              void* d_out, int out_size, void* d_ws, size_t ws_size,
                              hipStream_t stream) {
    const float* data = (const float*)d_in[0];
    const float* cen0 = (const float*)d_in[1];
    float* out = (float*)d_out;
    char* ws = (char*)d_ws;

    float* wcen   = (float*)(ws + 0);
    int*   flag   = (int*)(ws + 4096);
    int*   cntinr = (int*)(ws + 8192);
    int*   ctot   = (int*)(ws + 8704);
    int*   cbase  = (int*)(ws + 9216);
    float* sums   = (float*)(ws + 9728);
    int*   bh     = (int*)(ws + 16384);
    int*   idxl   = (int*)(ws + 16384 + (size_t)NUMC * NBLK * 4);
    int*   labels = (int*)d_out;   // staged as int32, converted by k_finish

    k_init<<<4, 256, 0, stream>>>(cen0, wcen, flag);
    for (int it = 0; it < ITERS; ++it) {
        k_zero   <<<1, 256, 0, stream>>>(cntinr);
        k_count  <<<NBLK, 256, 0, stream>>>(data, wcen, cntinr, flag);
        k_assign <<<NBLK, 256, 0, stream>>>(data, wcen, cntinr, labels, bh, flag);
        k_scan   <<<NUMC, 256, 0, stream>>>(bh, ctot, flag);
        k_base   <<<1, 64, 0, stream>>>(ctot, cbase, flag);
        k_scatter<<<NBLK, 256, 0, stream>>>(labels, bh, cbase, idxl, flag);
        k_sums   <<<NUMC, 64, 0, stream>>>(data, idxl, cbase, ctot, sums, flag);
        k_update <<<1, 256, 0, stream>>>(wcen, sums, ctot, flag);
    }
    k_finish<<<(NPTS + NUMC * FD + 255) / 256, 256, 0, stream>>>(out, wcen);
}

// Round 2
// 2655.515 us; speedup vs baseline: 6.8105x; 6.8105x over previous
//
#include <hip/hip_runtime.h>

// Problem constants (fixed by the reference file)
#define NPTS 524288
#define NUMC 128
#define FD   8
#define NBLK 2048          // NPTS / 256
#define ITERS 5

// k_sums chunking: CH members per LDS chunk, feature-major with pad
#define CH    512
#define CHPAD 516          // %4==0 (float4 aligned), 516%32=4 -> lanes 0..7 hit disjoint bank groups

static_assert(NPTS == NBLK * 256, "grid must tile N exactly");

// ---- workspace layout (bytes) ----
// 0       : centers   float[1024]
// 4096    : flag      int
// 8192    : cnt_inr   int[128]
// 8704    : ctot      int[128]
// 9216    : cbase     int[128]
// 9728    : sums      float[1024]
// 16384   : blockhist int[128*2048]   (1 MB) — cluster-major
// 1064960 : idxlist   int[NPTS]       (2 MB)

__global__ void k_init(const float* __restrict__ cin, float* __restrict__ cen, int* __restrict__ flag) {
    int t = blockIdx.x * 256 + threadIdx.x;
    if (t < NUMC * FD) cen[t] = cin[t];
    if (t == 0) *flag = 0;
}

__global__ void k_zero(int* __restrict__ cnt_inr) {
    int t = threadIdx.x;
    if (t < NUMC) cnt_inr[t] = 0;
}

// Pass A: per-center count of points with sqrt(dx^2+dy^2) <= 0.32 (exact recipe, matches assignment)
__global__ void k_count(const float* __restrict__ data, const float* __restrict__ cen,
                        int* __restrict__ cnt_inr, const int* __restrict__ flag) {
    if (*flag) return;
    __shared__ float cx[NUMC], cy[NUMC];
    __shared__ int hist[NUMC];
    int tid = threadIdx.x;
    if (tid < NUMC) { cx[tid] = cen[tid * FD]; cy[tid] = cen[tid * FD + 1]; hist[tid] = 0; }
    __syncthreads();
    size_t j = (size_t)blockIdx.x * 256 + tid;
    float2 p = *(const float2*)(data + j * FD);
    int lane = tid & 63;
    for (int i = 0; i < NUMC; i++) {
        float dx = __fsub_rn(p.x, cx[i]);
        float dy = __fsub_rn(p.y, cy[i]);
        float s  = __fadd_rn(__fmul_rn(dx, dx), __fmul_rn(dy, dy));
        bool in  = (__fsqrt_rn(s) <= 0.32f);
        unsigned long long m = __ballot(in);
        if (lane == 0 && m) atomicAdd(&hist[i], __popcll(m));
    }
    __syncthreads();
    if (tid < NUMC && hist[tid]) atomicAdd(&cnt_inr[tid], hist[tid]);
}

// Pass B: sequential-per-center assignment chain with the freeze quirk.
// Emits a per-block, cluster-major label histogram for the stable counting sort.
__global__ void k_assign(const float* __restrict__ data, const float* __restrict__ cen,
                         const int* __restrict__ cnt_inr, int* __restrict__ labels,
                         int* __restrict__ blockhist, const int* __restrict__ flag) {
    if (*flag) return;
    __shared__ float C[NUMC * FD];
    __shared__ int enough[NUMC];
    __shared__ int hist[NUMC];
    int tid = threadIdx.x;
    for (int e = tid; e < NUMC * FD; e += 256) C[e] = cen[e];
    if (tid < NUMC) { enough[tid] = (cnt_inr[tid] > 1); hist[tid] = 0; }
    __syncthreads();
    size_t j = (size_t)blockIdx.x * 256 + tid;
    float4 a = *(const float4*)(data + j * FD);
    float4 b = *(const float4*)(data + j * FD + 4);
    float x[8] = {a.x, a.y, a.z, a.w, b.x, b.y, b.z, b.w};
    int lab = -1;
    float dval = 1000.0f;
    for (int i = 0; i < NUMC; i++) {
        const float* c = &C[i * FD];
        float dx = __fsub_rn(x[0], c[0]);
        float dy = __fsub_rn(x[1], c[1]);
        float s  = __fadd_rn(__fmul_rn(dx, dx), __fmul_rn(dy, dy));
        float sp = __fsqrt_rn(s);
        if (sp <= 0.32f && enough[i]) {
            float t0 = __fadd_rn(__fsub_rn(x[0], c[0]), 1e-6f);
            float ss = __fmul_rn(t0, t0);
            #pragma unroll
            for (int f = 1; f < 8; f++) {
                float tf = __fadd_rn(__fsub_rn(x[f], c[f]), 1e-6f);
                ss = __fadd_rn(ss, __fmul_rn(tf, tf));
            }
            float D = __fsqrt_rn(ss);
            if (D < dval) { dval = D; lab = i; }
            else break;   // reference sets dval=0 -> frozen forever
        }
    }
    labels[j] = lab;
    if (lab >= 0) atomicAdd(&hist[lab], 1);
    __syncthreads();
    if (tid < NUMC) blockhist[tid * NBLK + blockIdx.x] = hist[tid];
}

// Per-cluster exclusive scan over the 2048 block counts
__global__ void k_scan(int* __restrict__ blockhist, int* __restrict__ ctot, const int* __restrict__ flag) {
    if (*flag) return;
    int c = blockIdx.x, tid = threadIdx.x;
    __shared__ int ts[256];
    int base = c * NBLK + tid * 8;
    int v[8], s = 0;
    #pragma unroll
    for (int u = 0; u < 8; u++) { v[u] = blockhist[base + u]; s += v[u]; }
    ts[tid] = s;
    __syncthreads();
    for (int off = 1; off < 256; off <<= 1) {
        int t = (tid >= off) ? ts[tid - off] : 0;
        __syncthreads();
        ts[tid] += t;
        __syncthreads();
    }
    int run = (tid == 0) ? 0 : ts[tid - 1];
    #pragma unroll
    for (int u = 0; u < 8; u++) { int t = v[u]; blockhist[base + u] = run; run += t; }
    if (tid == 255) ctot[c] = run;
}

__global__ void k_base(const int* __restrict__ ctot, int* __restrict__ cbase, const int* __restrict__ flag) {
    if (*flag) return;
    if (threadIdx.x == 0) {
        int r = 0;
        for (int c = 0; c < NUMC; c++) { cbase[c] = r; r += ctot[c]; }
    }
}

// Stable scatter: member indices per cluster, ascending global point index
__global__ void k_scatter(const int* __restrict__ labels, const int* __restrict__ blockhist,
                          const int* __restrict__ cbase, int* __restrict__ idxlist,
                          const int* __restrict__ flag) {
    if (*flag) return;
    __shared__ int sl[256];
    int tid = threadIdx.x;
    int j = blockIdx.x * 256 + tid;
    sl[tid] = labels[j];
    __syncthreads();
    int c = sl[tid];
    if (c >= 0) {
        int rank = 0;
        for (int t = 0; t < tid; t++) rank += (sl[t] == c);
        idxlist[cbase[c] + blockhist[c * NBLK + blockIdx.x] + rank] = j;
    }
}

// Exact sequential fp32 segment sums, restructured for chain-latency:
// one block per cluster. Waves 1..3 gather the NEXT chunk of members into a
// feature-major LDS tile (double-buffered) while wave 0 lanes 0..7 run the 8
// per-feature serial add chains over the CURRENT chunk as ds_read_b128 +
// dependent v_add_f32 (identical add order -> bit-exact vs reference).
__device__ __forceinline__ void gather_chunk(const float* __restrict__ data,
                                             const int* __restrict__ idxlist,
                                             int base, int m, int t,
                                             float* __restrict__ buf,
                                             int g, int G) {
    int s = t * CH;
    int e = s + CH; if (e > m) e = m;
    for (int j = s + g; j < e; j += G) {
        int rid = idxlist[base + j];
        float4 a = *(const float4*)(data + (size_t)rid * FD);
        float4 b = *(const float4*)(data + (size_t)rid * FD + 4);
        int k = j - s;
        buf[0 * CHPAD + k] = a.x;
        buf[1 * CHPAD + k] = a.y;
        buf[2 * CHPAD + k] = a.z;
        buf[3 * CHPAD + k] = a.w;
        buf[4 * CHPAD + k] = b.x;
        buf[5 * CHPAD + k] = b.y;
        buf[6 * CHPAD + k] = b.z;
        buf[7 * CHPAD + k] = b.w;
    }
}

__global__ void __launch_bounds__(256) k_sums(const float* __restrict__ data,
                       const int* __restrict__ idxlist,
                       const int* __restrict__ cbase, const int* __restrict__ ctot,
                       float* __restrict__ sums, const int* __restrict__ flag) {
    if (*flag) return;
    __shared__ float sbuf[2][FD * CHPAD];
    int c = blockIdx.x;
    int tid = threadIdx.x;
    int wid = tid >> 6;
    int lane = tid & 63;
    int m = ctot[c], base = cbase[c];
    int nch = (m + CH - 1) / CH;
    float acc = 0.0f;

    if (nch > 0) {
        // prologue: everyone gathers chunk 0
        gather_chunk(data, idxlist, base, m, 0, sbuf[0], tid, 256);
        __syncthreads();
        for (int t = 0; t < nch; t++) {
            if (wid != 0) {
                if (t + 1 < nch)
                    gather_chunk(data, idxlist, base, m, t + 1, sbuf[(t + 1) & 1], tid - 64, 192);
            } else if (lane < FD) {
                const float* col = &sbuf[t & 1][lane * CHPAD];
                int lim = m - t * CH; if (lim > CH) lim = CH;
                int k = 0;
                for (; k + 16 <= lim; k += 16) {
                    float4 a  = *(const float4*)(col + k);
                    float4 b  = *(const float4*)(col + k + 4);
                    float4 c2 = *(const float4*)(col + k + 8);
                    float4 d  = *(const float4*)(col + k + 12);
                    acc = __fadd_rn(acc, a.x);  acc = __fadd_rn(acc, a.y);
                    acc = __fadd_rn(acc, a.z);  acc = __fadd_rn(acc, a.w);
                    acc = __fadd_rn(acc, b.x);  acc = __fadd_rn(acc, b.y);
                    acc = __fadd_rn(acc, b.z);  acc = __fadd_rn(acc, b.w);
                    acc = __fadd_rn(acc, c2.x); acc = __fadd_rn(acc, c2.y);
                    acc = __fadd_rn(acc, c2.z); acc = __fadd_rn(acc, c2.w);
                    acc = __fadd_rn(acc, d.x);  acc = __fadd_rn(acc, d.y);
                    acc = __fadd_rn(acc, d.z);  acc = __fadd_rn(acc, d.w);
                }
                for (; k < lim; k++) acc = __fadd_rn(acc, col[k]);
            }
            __syncthreads();
        }
    }
    if (wid == 0 && lane < FD) sums[c * FD + lane] = acc;
}

// Center update + convergence flag (1 block)
__global__ void k_update(float* __restrict__ cen, const float* __restrict__ sums,
                         const int* __restrict__ ctot, int* __restrict__ flag) {
    if (*flag) return;
    __shared__ float red[256];
    int tid = threadIdx.x;
    float sq = 0.0f;
    float newv[4];
    int   eidx[4];
    int ne = 0;
    for (int e = tid; e < NUMC * FD; e += 256) {
        int c = e >> 3;
        float oldv = cen[e];
        float cntf = (float)ctot[c];
        float mean = __fdiv_rn(sums[e], fmaxf(cntf, 1.0f));
        float nc = (cntf > 0.0f) ? mean : oldv;
        float d = __fsub_rn(nc, oldv);
        sq = __fadd_rn(sq, __fmul_rn(d, d));
        newv[ne] = nc; eidx[ne] = e; ne++;
    }
    red[tid] = sq;
    __syncthreads();
    for (int off = 128; off > 0; off >>= 1) {
        if (tid < off) red[tid] += red[tid + off];
        __syncthreads();
    }
    for (int u = 0; u < ne; u++) cen[eidx[u]] = newv[u];
    if (tid == 0) {
        float diff = __fsqrt_rn(red[0]);
        if (diff < 1e-4f) *flag = 1;
    }
}

// Finalize: labels staged as int32 in d_out[0..N); convert to float, append centers.
__global__ void k_finish(float* __restrict__ out, const float* __restrict__ cen) {
    size_t i = (size_t)blockIdx.x * 256 + threadIdx.x;
    if (i < NPTS) {
        int v = ((const int*)out)[i];
        out[i] = (float)v;
    } else if (i < NPTS + NUMC * FD) {
        out[i] = cen[i - NPTS];
    }
}

extern "C" void kernel_launch(void* const* d_in, const int* in_sizes, int n_in,
                              void* d_out, int out_size, void* d_ws, size_t ws_size,
                              hipStream_t stream) {
    const float* data = (const float*)d_in[0];
    const float* cen0 = (const float*)d_in[1];
    float* out = (float*)d_out;
    char* ws = (char*)d_ws;

    float* wcen   = (float*)(ws + 0);
    int*   flag   = (int*)(ws + 4096);
    int*   cntinr = (int*)(ws + 8192);
    int*   ctot   = (int*)(ws + 8704);
    int*   cbase  = (int*)(ws + 9216);
    float* sums   = (float*)(ws + 9728);
    int*   bh     = (int*)(ws + 16384);
    int*   idxl   = (int*)(ws + 16384 + (size_t)NUMC * NBLK * 4);
    int*   labels = (int*)d_out;   // staged as int32, converted by k_finish

    k_init<<<4, 256, 0, stream>>>(cen0, wcen, flag);
    for (int it = 0; it < ITERS; ++it) {
        k_zero   <<<1, 256, 0, stream>>>(cntinr);
        k_count  <<<NBLK, 256, 0, stream>>>(data, wcen, cntinr, flag);
        k_assign <<<NBLK, 256, 0, stream>>>(data, wcen, cntinr, labels, bh, flag);
        k_scan   <<<NUMC, 256, 0, stream>>>(bh, ctot, flag);
        k_base   <<<1, 64, 0, stream>>>(ctot, cbase, flag);
        k_scatter<<<NBLK, 256, 0, stream>>>(labels, bh, cbase, idxl, flag);
        k_sums   <<<NUMC, 256, 0, stream>>>(data, idxl, cbase, ctot, sums, flag);
        k_update <<<1, 256, 0, stream>>>(wcen, sums, ctot, flag);
    }
    k_finish<<<(NPTS + NUMC * FD + 255) / 256, 256, 0, stream>>>(out, wcen);
}